// Round 1
// baseline (205.021 us; speedup 1.0000x reference)
//
#include <hip/hip_runtime.h>
#include <math.h>

#define E 2048
#define R 24
#define F 128
#define NSLOPE 0.2f

__device__ __forceinline__ float lrelu(float x){ return x > 0.f ? x : NSLOPE*x; }

// ---------------- K1: adj_sm = softmax(A, axis=1)  [E,R] ----------------
__global__ void k_softmaxA(const float* __restrict__ A, float* __restrict__ adj_sm){
  int e = blockIdx.x*blockDim.x + threadIdx.x;
  if (e >= E) return;
  float v[R]; float m = -1e30f;
  #pragma unroll
  for (int r=0;r<R;++r){ v[r] = A[e*R+r]; m = fmaxf(m, v[r]); }
  float s = 0.f;
  #pragma unroll
  for (int r=0;r<R;++r){ v[r] = __expf(v[r]-m); s += v[r]; }
  float inv = 1.f/s;
  #pragma unroll
  for (int r=0;r<R;++r) adj_sm[e*R+r] = v[r]*inv;
}

// ---------------- K2: column (over-e) softmax partial stats for att_E ----
#define CH 16
#define ECH (E/CH)
__global__ void k_colstats(const float* __restrict__ ent, const float* __restrict__ rel,
                           const float* __restrict__ adj_sm,
                           float* __restrict__ pmax, float* __restrict__ psum){
  int f = threadIdx.x; int r = blockIdx.x; int c = blockIdx.y;
  float relv = rel[r*F+f];
  float m = -1e30f, s = 0.f;
  int e0 = c*ECH;
  for (int e=e0; e<e0+ECH; ++e){
    float x = lrelu(adj_sm[e*R+r] * ent[e*F+f] * relv);
    float mn = fmaxf(m, x);
    s = s*__expf(m-mn) + __expf(x-mn);
    m = mn;
  }
  pmax[(r*CH+c)*F+f] = m;
  psum[(r*CH+c)*F+f] = s;
}

__global__ void k_colreduce(const float* __restrict__ pmax, const float* __restrict__ psum,
                            float* __restrict__ colmax, float* __restrict__ colinv){
  int idx = blockIdx.x*blockDim.x + threadIdx.x;
  if (idx >= R*F) return;
  int r = idx / F, f = idx % F;
  float M = -1e30f;
  for (int c=0;c<CH;++c) M = fmaxf(M, pmax[(r*CH+c)*F+f]);
  float S = 0.f;
  for (int c=0;c<CH;++c) S += psum[(r*CH+c)*F+f]*__expf(pmax[(r*CH+c)*F+f]-M);
  colmax[idx]=M; colinv[idx]=1.f/S;
}

// ---------------- K4: h_prime -> d_out, srow = sum_e att_R ----------------
#define EBH 16
__global__ void k_h_srow(const float* __restrict__ ent, const float* __restrict__ rel,
                         const float* __restrict__ adj_sm, const float* __restrict__ colmax,
                         const float* __restrict__ colinv, float* __restrict__ out_h,
                         float* __restrict__ srow){
  int f = threadIdx.x; int e0 = blockIdx.x*EBH;
  float relv[R], cm[R], ci[R], sR[R];
  #pragma unroll
  for (int r=0;r<R;++r){ relv[r]=rel[r*F+f]; cm[r]=colmax[r*F+f]; ci[r]=colinv[r*F+f]; sR[r]=0.f; }
  for (int e=e0; e<e0+EBH; ++e){
    float entv = ent[e*F+f];
    float att[R]; float rm=-1e30f;
    #pragma unroll
    for (int r=0;r<R;++r){ float x = lrelu(adj_sm[e*R+r]*entv*relv[r]); att[r]=x; rm=fmaxf(rm,x); }
    float rs=0.f; float ex[R];
    #pragma unroll
    for (int r=0;r<R;++r){ ex[r]=__expf(att[r]-rm); rs+=ex[r]; }
    float invrs=1.f/rs;
    float sumE=0.f;
    #pragma unroll
    for (int r=0;r<R;++r){ sumE += __expf(att[r]-cm[r])*ci[r]; sR[r] += ex[r]*invrs; }
    out_h[e*F+f] = entv*sumE;
  }
  #pragma unroll
  for (int r=0;r<R;++r) atomicAdd(&srow[r*F+f], sR[r]);
}

// ---------------- K5: alpha_lin[e,r] = sum_f att_R*lin_w + b  (flat [E][R]) ----
__global__ void k_alpha_lin(const float* __restrict__ ent, const float* __restrict__ rel,
                            const float* __restrict__ adj_sm, const float* __restrict__ lin_w,
                            const float* __restrict__ lin_b, float* __restrict__ alin){
  int w = threadIdx.x >> 6, lane = threadIdx.x & 63;
  int e = blockIdx.x*4 + w;
  float p[R];
  #pragma unroll
  for (int r=0;r<R;++r) p[r]=0.f;
  #pragma unroll
  for (int h=0; h<2; ++h){
    int f = lane + 64*h;
    float entv = ent[e*F+f];
    float lw = lin_w[f];
    float att[R]; float rm = -1e30f;
    #pragma unroll
    for (int r=0;r<R;++r){ float x = lrelu(adj_sm[e*R+r]*entv*rel[r*F+f]); att[r]=x; rm=fmaxf(rm,x); }
    float rs=0.f; float ex[R];
    #pragma unroll
    for (int r=0;r<R;++r){ ex[r]=__expf(att[r]-rm); rs+=ex[r]; }
    float invrs = 1.f/rs;
    #pragma unroll
    for (int r=0;r<R;++r) p[r] += ex[r]*invrs*lw;
  }
  #pragma unroll
  for (int off=32; off>=1; off>>=1){
    #pragma unroll
    for (int r=0;r<R;++r) p[r] += __shfl_xor(p[r], off);
  }
  if (lane==0){
    float lb = lin_b[0];
    #pragma unroll
    for (int r=0;r<R;++r) alin[e*R+r] = p[r]+lb;
  }
}

// ---------------- K6: alpha = softmax over e of alin viewed as [R][E] -----
__global__ void k_alpha_sm(const float* __restrict__ alin, float* __restrict__ alpha){
  __shared__ float red[256];
  int r = blockIdx.x, t = threadIdx.x;
  float v[8]; float m = -1e30f;
  #pragma unroll
  for (int i=0;i<8;++i){ v[i] = alin[r*E + i*256 + t]; m = fmaxf(m, v[i]); }
  red[t] = m; __syncthreads();
  for (int s=128; s>0; s>>=1){ if (t<s) red[t] = fmaxf(red[t], red[t+s]); __syncthreads(); }
  m = red[0]; __syncthreads();
  float sum=0.f;
  #pragma unroll
  for (int i=0;i<8;++i){ v[i] = __expf(v[i]-m); sum += v[i]; }
  red[t] = sum; __syncthreads();
  for (int s=128; s>0; s>>=1){ if (t<s) red[t] += red[t+s]; __syncthreads(); }
  float inv = 1.f/red[0];
  #pragma unroll
  for (int i=0;i<8;++i) alpha[r*E + i*256 + t] = v[i]*inv;
}

// ---------------- K7: rel_output = (rel .* srow) @ weight_rel -------------
__global__ void k_relout(const float* __restrict__ rel, const float* __restrict__ srow,
                         const float* __restrict__ wrel, float* __restrict__ out_rel){
  int fo = threadIdx.x; int r = blockIdx.x;
  float acc = 0.f;
  for (int fi=0; fi<F; ++fi) acc += rel[r*F+fi]*srow[r*F+fi]*wrel[fi*F+fo];
  out_rel[r*F+fo] = acc;
}

// ---------------- K8: W2 = ent @ weight_ent -------------------------------
__global__ void k_W2(const float* __restrict__ ent, const float* __restrict__ went,
                     float* __restrict__ W2){
  int fo = threadIdx.x; int e0 = blockIdx.x*8;
  float acc[8];
  #pragma unroll
  for (int k=0;k<8;++k) acc[k]=0.f;
  for (int fi=0; fi<F; ++fi){
    float wv = went[fi*F+fo];
    #pragma unroll
    for (int k=0;k<8;++k) acc[k] += ent[(e0+k)*F+fi]*wv;
  }
  #pragma unroll
  for (int k=0;k<8;++k) W2[(e0+k)*F+fo] = acc[k];
}

// ---------------- K9: out += B @ W2,  B[e,j] = sum_r alpha[r,e]*adj[r,e,j] -
__global__ __launch_bounds__(256) void k_main(const float* __restrict__ adj,
        const float* __restrict__ alpha, const float* __restrict__ W2,
        float* __restrict__ out){
  __shared__ float W2lds[64*F];   // 32 KB
  __shared__ float Blds[4*64];
  __shared__ float alds[4*R];
  int t = threadIdx.x;
  int e0 = blockIdx.x*4;
  if (t < 4*R) alds[t] = alpha[(t % R)*E + e0 + (t / R)];
  __syncthreads();
  int f = t & 127, grp = t >> 7;
  int esB = t >> 6, jB = t & 63;
  float a_r[R];
  #pragma unroll
  for (int r=0;r<R;++r) a_r[r] = alds[esB*R + r];
  float acc0=0.f, acc1=0.f;
  for (int j0=0; j0<E; j0+=64){
    // phase 1: compute 4x64 tile of B (streams adjacencies from HBM)
    float b = 0.f;
    #pragma unroll
    for (int r=0;r<R;++r)
      b += a_r[r] * adj[((size_t)r*E + e0 + esB)*(size_t)E + j0 + jB];
    __syncthreads();          // previous phase-2 readers done
    Blds[esB*64 + jB] = b;
    float4* dst = (float4*)W2lds;
    const float4* src = (const float4*)(W2 + j0*F);
    #pragma unroll
    for (int i=0;i<8;++i) dst[i*256+t] = src[i*256+t];
    __syncthreads();
    // phase 2: acc += B_tile @ W2_tile
    #pragma unroll 16
    for (int jj=0; jj<64; ++jj){
      float wv = W2lds[jj*F + f];
      acc0 += Blds[grp*64 + jj]*wv;
      acc1 += Blds[(grp+2)*64 + jj]*wv;
    }
  }
  int i0 = (e0+grp)*F + f;
  int i1 = (e0+grp+2)*F + f;
  out[i0] += acc0;            // h_prime already there
  out[i1] += acc1;
}

extern "C" void kernel_launch(void* const* d_in, const int* in_sizes, int n_in,
                              void* d_out, int out_size, void* d_ws, size_t ws_size,
                              hipStream_t stream) {
  const float* ent  = (const float*)d_in[0];
  const float* rel  = (const float*)d_in[1];
  const float* adj  = (const float*)d_in[2];
  const float* A    = (const float*)d_in[3];
  const float* went = (const float*)d_in[4];
  const float* wrel = (const float*)d_in[5];
  const float* linw = (const float*)d_in[6];
  const float* linb = (const float*)d_in[7];
  float* out = (float*)d_out;

  float* ws = (float*)d_ws;
  float* adj_sm  = ws;                    // 49152
  float* pmax    = adj_sm + E*R;          // 49152
  float* psum    = pmax + R*CH*F;         // 49152
  float* colmax  = psum + R*CH*F;         // 3072
  float* colinv  = colmax + R*F;          // 3072
  float* srow    = colinv + R*F;          // 3072
  float* alin    = srow + R*F;            // 49152
  float* alpha   = alin + E*R;            // 49152
  float* W2      = alpha + E*R;           // 262144

  k_softmaxA<<<dim3((E+255)/256), dim3(256), 0, stream>>>(A, adj_sm);
  k_colstats<<<dim3(R, CH), dim3(F), 0, stream>>>(ent, rel, adj_sm, pmax, psum);
  k_colreduce<<<dim3((R*F+255)/256), dim3(256), 0, stream>>>(pmax, psum, colmax, colinv);
  hipMemsetAsync(srow, 0, R*F*sizeof(float), stream);
  k_h_srow<<<dim3(E/EBH), dim3(F), 0, stream>>>(ent, rel, adj_sm, colmax, colinv, out, srow);
  k_alpha_lin<<<dim3(E/4), dim3(256), 0, stream>>>(ent, rel, adj_sm, linw, linb, alin);
  k_alpha_sm<<<dim3(R), dim3(256), 0, stream>>>(alin, alpha);
  k_relout<<<dim3(R), dim3(F), 0, stream>>>(rel, srow, wrel, out + E*F);
  k_W2<<<dim3(E/8), dim3(F), 0, stream>>>(ent, went, W2);
  k_main<<<dim3(E/4), dim3(256), 0, stream>>>(adj, alpha, W2, out);
}